// Round 1
// baseline (862.508 us; speedup 1.0000x reference)
//
#include <hip/hip_runtime.h>
#include <math.h>

// FlowMamba on MI355X. fp32 correctness-first implementation.
// Dims (compile-time): B=1, T_IN=4, PRED_LEN=4, C_IN=1, D_MODEL=64, D_STATE=16,
// H=W=32 (HW=1024), NV=25 velocities (V_RANGE=2).
//
// Workspace layout (floats):
//   S    : 25*64*16*1024  (state, updated IN PLACE per step; step0 writes only)
//   ABAR : 64*16*1024     (exp(delta*A), v-independent, recomputed per step)
//   BV   : 16*1024
//   CV   : 16*1024
//   U    : 64*1024        (encoder output)
//   X1   : 64*1024        (encoder intermediate)
//   Y    : 25*64*1024     (per-v y, dec steps only)
//   YMAX : 64*1024
//   D1,D2: 64*1024 each   (decoder intermediates)
// total ~112 MB.

#define NV 25

__device__ __forceinline__ float softplus_f(float x) {
    return fmaxf(x, 0.f) + log1pf(expf(-fabsf(x)));
}

// Cooperative circular 3x3 conv accumulator.
// Block: 256 threads = 8 rows x 32 cols, computing 1 px/thread for one output
// channel over rows [rb, rb+8). Input (CIN x 32 x 32) staged in LDS in chunks
// of <=32 channels (10 rows incl. wrap halo per channel = 320 floats).
// wgt must already point at this output channel's CIN*9 weights.
template<int CIN>
__device__ __forceinline__ float conv_acc(const float* __restrict__ in,
                                          const float* __restrict__ wgt,
                                          int rb, int lr, int c,
                                          float* __restrict__ smem)
{
    const int t = threadIdx.x;
    const int cm1 = (c + 31) & 31, cp1 = (c + 1) & 31;
    constexpr int CH = (CIN < 32) ? CIN : 32;
    float acc = 0.f;
    for (int c0 = 0; c0 < CIN; c0 += CH) {
        if (c0) __syncthreads();   // protect smem reuse across chunks
        for (int idx = t; idx < CH * 320; idx += 256) {
            int ci  = idx / 320;
            int rem = idx - ci * 320;
            int gr  = (rb - 1 + (rem >> 5)) & 31;   // global row, wrapped
            smem[idx] = in[((c0 + ci) << 10) + (gr << 5) + (rem & 31)];
        }
        __syncthreads();
        for (int ci = 0; ci < CH; ++ci) {
            const float* lp = smem + ci * 320 + lr * 32; // stage row lr == global row rb+lr-1
            const float* wp = wgt + (c0 + ci) * 9;       // uniform -> s_load
            acc += wp[0]*lp[cm1]    + wp[1]*lp[c]    + wp[2]*lp[cp1];
            acc += wp[3]*lp[32+cm1] + wp[4]*lp[32+c] + wp[5]*lp[32+cp1];
            acc += wp[6]*lp[64+cm1] + wp[7]*lp[64+c] + wp[8]*lp[64+cp1];
        }
    }
    return acc;
}

// Generic conv: grid (COUT, 4 row-strips), bias always present.
template<int CIN, int ACT>   // ACT: 0 none, 1 relu
__global__ __launch_bounds__(256) void conv3x3_k(const float* __restrict__ in,
        const float* __restrict__ wgt, const float* __restrict__ bias,
        float* __restrict__ out)
{
    __shared__ float smem[((CIN < 32) ? CIN : 32) * 320];
    const int co = blockIdx.x;
    const int rb = blockIdx.y * 8;
    const int t = threadIdx.x;
    const int c = t & 31, lr = t >> 5;
    float acc = conv_acc<CIN>(in, wgt + co * CIN * 9, rb, lr, c, smem) + bias[co];
    if (ACT) acc = fmaxf(acc, 0.f);
    out[(co << 10) + ((rb + lr) << 5) + c] = acc;
}

// Fused cell convs: co in [0,64) -> delta conv (wd,bd,+dt_inv,softplus) then
// ABAR[d,n,px] = exp(delta*A[d,n]) written directly (delta never materialized);
// co in [64,80) -> Bv (wB, no bias); co in [80,96) -> Cv (wC, no bias).
__global__ __launch_bounds__(256) void cellconv_k(const float* __restrict__ u,
        const float* __restrict__ wd, const float* __restrict__ bd,
        const float* __restrict__ wB, const float* __restrict__ wC,
        const float* __restrict__ logA, const float* __restrict__ dtinv,
        float* __restrict__ abar, float* __restrict__ Bv, float* __restrict__ Cv)
{
    __shared__ float smem[32 * 320];
    const int co = blockIdx.x;     // 0..95
    const int rb = blockIdx.y * 8;
    const int t = threadIdx.x;
    const int c = t & 31, lr = t >> 5;
    const float* wgt = (co < 64) ? (wd + co * 576)
                     : (co < 80) ? (wB + (co - 64) * 576)
                                 : (wC + (co - 80) * 576);
    float acc = conv_acc<64>(u, wgt, rb, lr, c, smem);
    const int px = ((rb + lr) << 5) + c;
    if (co < 64) {
        float sp = softplus_f(acc + bd[co] + dtinv[0]);
        #pragma unroll
        for (int n = 0; n < 16; ++n) {
            float a = -expf(logA[co * 16 + n]);            // uniform per block
            abar[((co * 16 + n) << 10) + px] = expf(sp * a);
        }
    } else if (co < 80) {
        Bv[((co - 64) << 10) + px] = acc;
    } else {
        Cv[((co - 80) << 10) + px] = acc;
    }
}

// State update, IN PLACE. Block (v,d) owns slab s[v][d][0:16][0:1024].
// s_new[n,hw] = abar[d,n,hw]*s[n, shift_v(hw)] + (abar-1)/A[d,n]*Bv[n,hw]*u[d,hw]
// All reads (shifted) land in registers, __syncthreads, then write back.
// Also accumulates y[v,d,hw] = sum_n s_new*Cv[n,hw] (stored iff computeY).
__global__ __launch_bounds__(256) void state_k(float* __restrict__ s,
        const float* __restrict__ abar, const float* __restrict__ Bv,
        const float* __restrict__ u, const float* __restrict__ logA,
        const float* __restrict__ Cv, float* __restrict__ y,
        int first, int computeY)
{
    const int v = blockIdx.x, d = blockIdx.y;
    const int vx = v / 5 - 2, vy = v % 5 - 2;   // V_LIST: x outer, y inner
    const int t = threadIdx.x;
    const int sbase = ((v << 6) + d) << 14;     // *16*1024
    int hw[4], sid[4];
    float ud[4], yacc[4];
    #pragma unroll
    for (int k = 0; k < 4; ++k) {
        hw[k] = t + (k << 8);
        int h = hw[k] >> 5, w = hw[k] & 31;
        sid[k] = (((h + vy) & 31) << 5) | ((w + vx) & 31);  // roll(-vy,-vx)
        ud[k] = u[(d << 10) + hw[k]];
        yacc[k] = 0.f;
    }
    float sn[16][4];
    if (first) {
        #pragma unroll
        for (int n = 0; n < 16; ++n) {
            float a = -expf(logA[(d << 4) + n]);
            float inva = 1.f / a;
            const int pb = ((d << 4) + n) << 10;
            #pragma unroll
            for (int k = 0; k < 4; ++k) {
                float ab = abar[pb + hw[k]];
                float bb = (ab - 1.f) * inva * Bv[(n << 10) + hw[k]];
                float ns = bb * ud[k];
                sn[n][k] = ns;
                yacc[k] = fmaf(ns, Cv[(n << 10) + hw[k]], yacc[k]);
            }
        }
    } else {
        #pragma unroll
        for (int n = 0; n < 16; ++n) {
            float a = -expf(logA[(d << 4) + n]);
            float inva = 1.f / a;
            const int pb = ((d << 4) + n) << 10;
            #pragma unroll
            for (int k = 0; k < 4; ++k) {
                float ab = abar[pb + hw[k]];
                float bb = (ab - 1.f) * inva * Bv[(n << 10) + hw[k]];
                float sv = s[sbase + (n << 10) + sid[k]];
                float ns = fmaf(ab, sv, bb * ud[k]);
                sn[n][k] = ns;
                yacc[k] = fmaf(ns, Cv[(n << 10) + hw[k]], yacc[k]);
            }
        }
        __syncthreads();   // all slab reads drained before any write
    }
    #pragma unroll
    for (int n = 0; n < 16; ++n)
        #pragma unroll
        for (int k = 0; k < 4; ++k)
            s[sbase + (n << 10) + hw[k]] = sn[n][k];
    if (computeY) {
        #pragma unroll
        for (int k = 0; k < 4; ++k)
            y[(((v << 6) + d) << 10) + hw[k]] = yacc[k];
    }
}

// ymax[d,hw] = max_v y[v,d,hw] + u[d,hw]*Dskip[d]  (u*Dskip is v-uniform)
__global__ __launch_bounds__(256) void ymax_k(const float* __restrict__ y,
        const float* __restrict__ u, const float* __restrict__ Dskip,
        float* __restrict__ ymax)
{
    const int d = blockIdx.x;
    const int t = threadIdx.x;
    #pragma unroll
    for (int k = 0; k < 4; ++k) {
        int hw = t + (k << 8);
        float m = -1e30f;
        for (int v = 0; v < NV; ++v)
            m = fmaxf(m, y[((v * 64 + d) << 10) + hw]);
        ymax[(d << 10) + hw] = m + u[(d << 10) + hw] * Dskip[d];
    }
}

extern "C" void kernel_launch(void* const* d_in, const int* in_sizes, int n_in,
                              void* d_out, int out_size, void* d_ws, size_t ws_size,
                              hipStream_t stream)
{
    const float* input_seq = (const float*)d_in[0];
    const float* enc_w1 = (const float*)d_in[1];
    const float* enc_b1 = (const float*)d_in[2];
    const float* enc_w2 = (const float*)d_in[3];
    const float* enc_b2 = (const float*)d_in[4];
    const float* wd     = (const float*)d_in[5];
    const float* bd     = (const float*)d_in[6];
    const float* wB     = (const float*)d_in[7];
    const float* wC     = (const float*)d_in[8];
    const float* logA   = (const float*)d_in[9];
    const float* Dskip  = (const float*)d_in[10];
    const float* dtinv  = (const float*)d_in[11];
    const float* dec_w1 = (const float*)d_in[12];
    const float* dec_b1 = (const float*)d_in[13];
    const float* dec_w2 = (const float*)d_in[14];
    const float* dec_b2 = (const float*)d_in[15];
    const float* dec_w3 = (const float*)d_in[16];
    const float* dec_b3 = (const float*)d_in[17];
    // d_in[18] = pred_len (known 4 at compile time)

    float* ws   = (float*)d_ws;
    float* S    = ws;                         // 26,214,400
    float* ABAR = S + 25 * 64 * 16 * 1024;    // 1,048,576
    float* BV   = ABAR + 64 * 16 * 1024;      // 16,384
    float* CV   = BV + 16 * 1024;             // 16,384
    float* U    = CV + 16 * 1024;             // 65,536
    float* X1   = U + 64 * 1024;              // 65,536
    float* Y    = X1 + 64 * 1024;             // 1,638,400
    float* YMAX = Y + 25 * 64 * 1024;         // 65,536
    float* D1   = YMAX + 64 * 1024;           // 65,536
    float* D2   = D1 + 64 * 1024;             // 65,536
    float* outp = (float*)d_out;              // 4 * 1024

    auto enc = [&](const float* src) {
        conv3x3_k<1, 1><<<dim3(64, 4), 256, 0, stream>>>(src, enc_w1, enc_b1, X1);
        conv3x3_k<64, 1><<<dim3(64, 4), 256, 0, stream>>>(X1, enc_w2, enc_b2, U);
    };
    auto cell = [&](int first, int computeY) {
        cellconv_k<<<dim3(96, 4), 256, 0, stream>>>(U, wd, bd, wB, wC, logA, dtinv,
                                                    ABAR, BV, CV);
        state_k<<<dim3(25, 64), 256, 0, stream>>>(S, ABAR, BV, U, logA, CV, Y,
                                                  first, computeY);
    };

    // Encode phase: scan over the 4 input frames (y unused).
    for (int tt = 0; tt < 4; ++tt) {
        enc(input_seq + tt * 1024);
        cell(tt == 0 ? 1 : 0, 0);
    }
    // Decode phase: autoregressive, feeding predictions back through the encoder.
    for (int tt = 0; tt < 4; ++tt) {
        enc(tt == 0 ? input_seq + 3 * 1024 : outp + (tt - 1) * 1024);
        cell(0, 1);
        ymax_k<<<64, 256, 0, stream>>>(Y, U, Dskip, YMAX);
        conv3x3_k<64, 1><<<dim3(64, 4), 256, 0, stream>>>(YMAX, dec_w1, dec_b1, D1);
        conv3x3_k<64, 1><<<dim3(64, 4), 256, 0, stream>>>(D1, dec_w2, dec_b2, D2);
        conv3x3_k<64, 0><<<dim3(1, 4), 256, 0, stream>>>(D2, dec_w3, dec_b3,
                                                         outp + tt * 1024);
    }
}

// Round 2
// 705.980 us; speedup vs baseline: 1.2217x; 1.2217x over previous
//
#include <hip/hip_runtime.h>
#include <math.h>

// FlowMamba on MI355X — round 2.
// B=1, T_IN=4, PRED_LEN=4, C_IN=1, D_MODEL=64, D_STATE=16, H=W=32, NV=25.
//
// Changes vs round 1:
//  * State stored bf16 (fp32 math): halves the dominant HBM stream.
//  * Entire 4-step encode scan fused into ONE kernel (state4_k) via the
//    unrolled recurrence (Horner over shifted reads) — no intermediate
//    state traffic at all; ABAR/BV/U for all 4 steps precomputed batched.
//  * ymax_k deleted: state_dec_k atomicMax's a monotonic-uint transform of y
//    into YMAXT (zeroed by cellconv_k); dec1_k untransforms + adds u*Dskip
//    during LDS staging.
//  * 32 kernel launches total (was 48).

#define NV 25

__device__ __forceinline__ float softplus_f(float x) {
    return fmaxf(x, 0.f) + log1pf(expf(-fabsf(x)));
}
__device__ __forceinline__ float bf2f(unsigned short u) {
    return __uint_as_float(((unsigned)u) << 16);
}
__device__ __forceinline__ unsigned short f2bf(float f) {
    unsigned b = __float_as_uint(f);
    b += 0x7fffu + ((b >> 16) & 1u);          // round-to-nearest-even
    return (unsigned short)(b >> 16);
}
// monotonic float<->uint order transform (for atomicMax on floats)
__device__ __forceinline__ unsigned f2ord(float f) {
    unsigned m = __float_as_uint(f);
    return (m & 0x80000000u) ? ~m : (m | 0x80000000u);
}
__device__ __forceinline__ float ord2f(unsigned m) {
    return (m & 0x80000000u) ? __uint_as_float(m & 0x7fffffffu)
                             : __uint_as_float(~m);
}

// ---------------------------------------------------------------------------
// Cooperative circular 3x3 conv accumulator (unchanged from round 1).
// Block: 256 thr = 8 rows x 32 cols, 1 px/thread, one output channel,
// rows [rb, rb+8). Input staged in LDS in <=32-channel chunks (10 rows each).
template<int CIN>
__device__ __forceinline__ float conv_acc(const float* __restrict__ in,
                                          const float* __restrict__ wgt,
                                          int rb, int lr, int c,
                                          float* __restrict__ smem)
{
    const int t = threadIdx.x;
    const int cm1 = (c + 31) & 31, cp1 = (c + 1) & 31;
    constexpr int CH = (CIN < 32) ? CIN : 32;
    float acc = 0.f;
    for (int c0 = 0; c0 < CIN; c0 += CH) {
        if (c0) __syncthreads();
        for (int idx = t; idx < CH * 320; idx += 256) {
            int ci  = idx / 320;
            int rem = idx - ci * 320;
            int gr  = (rb - 1 + (rem >> 5)) & 31;
            smem[idx] = in[((c0 + ci) << 10) + (gr << 5) + (rem & 31)];
        }
        __syncthreads();
        for (int ci = 0; ci < CH; ++ci) {
            const float* lp = smem + ci * 320 + lr * 32;
            const float* wp = wgt + (c0 + ci) * 9;
            acc += wp[0]*lp[cm1]    + wp[1]*lp[c]    + wp[2]*lp[cp1];
            acc += wp[3]*lp[32+cm1] + wp[4]*lp[32+c] + wp[5]*lp[32+cp1];
            acc += wp[6]*lp[64+cm1] + wp[7]*lp[64+c] + wp[8]*lp[64+cp1];
        }
    }
    return acc;
}

// Generic conv: grid (COUT, 4 strips, NB batch). in z-stride CIN*1024,
// out z-stride COUT(=gridDim.x)*1024.
template<int CIN, int ACT>
__global__ __launch_bounds__(256) void conv3x3_k(const float* __restrict__ in,
        const float* __restrict__ wgt, const float* __restrict__ bias,
        float* __restrict__ out)
{
    __shared__ float smem[((CIN < 32) ? CIN : 32) * 320];
    in  += (size_t)blockIdx.z * (CIN << 10);
    out += (size_t)blockIdx.z * (gridDim.x << 10);
    const int co = blockIdx.x;
    const int rb = blockIdx.y * 8;
    const int t = threadIdx.x;
    const int c = t & 31, lr = t >> 5;
    float acc = conv_acc<CIN>(in, wgt + co * CIN * 9, rb, lr, c, smem) + bias[co];
    if (ACT) acc = fmaxf(acc, 0.f);
    out[(co << 10) + ((rb + lr) << 5) + c] = acc;
}

// Fused cell convs, batched over t via blockIdx.z.
// co<64 -> ABAR[t,d,n,px] = exp(softplus(conv+bd+dtinv)*A[d,n]) (delta never
// materialized); co in [64,80) -> Bv; co in [80,96) -> Cv.
// zero_ymax: co<64 blocks also zero YMAXT (decode steps only).
__global__ __launch_bounds__(256) void cellconv_k(const float* __restrict__ u,
        const float* __restrict__ wd, const float* __restrict__ bd,
        const float* __restrict__ wB, const float* __restrict__ wC,
        const float* __restrict__ logA, const float* __restrict__ dtinv,
        float* __restrict__ abar, float* __restrict__ Bv, float* __restrict__ Cv,
        unsigned* __restrict__ ymaxt, int zero_ymax)
{
    __shared__ float smem[32 * 320];
    const int z = blockIdx.z;
    u    += (size_t)z << 16;       // [t][64][1024]
    abar += (size_t)z << 20;       // [t][64][16][1024]
    Bv   += (size_t)z << 14;       // [t][16][1024]
    Cv   += (size_t)z << 14;
    const int co = blockIdx.x;     // 0..95
    const int rb = blockIdx.y * 8;
    const int t = threadIdx.x;
    const int c = t & 31, lr = t >> 5;
    const float* wgt = (co < 64) ? (wd + co * 576)
                     : (co < 80) ? (wB + (co - 64) * 576)
                                 : (wC + (co - 80) * 576);
    float acc = conv_acc<64>(u, wgt, rb, lr, c, smem);
    const int px = ((rb + lr) << 5) + c;
    if (co < 64) {
        float sp = softplus_f(acc + bd[co] + dtinv[0]);
        #pragma unroll
        for (int n = 0; n < 16; ++n) {
            float a = -expf(logA[co * 16 + n]);
            abar[((co * 16 + n) << 10) + px] = expf(sp * a);
        }
        if (zero_ymax) ymaxt[(co << 10) + blockIdx.y * 256 + t] = 0u;
    } else if (co < 80) {
        Bv[((co - 64) << 10) + px] = acc;
    } else {
        Cv[((co - 80) << 10) + px] = acc;
    }
}

// ---------------------------------------------------------------------------
// ENTIRE 4-step encode scan in one kernel. Block (v,d) owns slab s[v][d].
// Unrolled recurrence (s_{-1}=0):
//   s3[p] = Horner over tau=0..3 of acc = ab_t[q]*acc + inj_t[q],
//   q = p + (3-tau)*Delta_v (circular), inj = (ab-1)/A * Bv * u   (all at q).
// Only reads ABAR/BV/U (L2/L3-resident), writes final state bf16 once.
__global__ __launch_bounds__(256) void state4_k(unsigned short* __restrict__ S,
        const float* __restrict__ abar, const float* __restrict__ Bv,
        const float* __restrict__ u, const float* __restrict__ logA)
{
    const int v = blockIdx.x, d = blockIdx.y;
    const int vx = v / 5 - 2, vy = v % 5 - 2;
    const int t = threadIdx.x;
    const size_t sbase = (size_t)((v << 6) + d) << 14;
    int sid[4][4];
    float uu[4][4];
    #pragma unroll
    for (int tau = 0; tau < 4; ++tau) {
        int sh = 3 - tau;
        #pragma unroll
        for (int k = 0; k < 4; ++k) {
            int p = t + (k << 8);
            int h = p >> 5, w = p & 31;
            int q = (((h + sh * vy + 32) & 31) << 5) | ((w + sh * vx + 32) & 31);
            sid[tau][k] = q;
            uu[tau][k] = u[(tau << 16) + (d << 10) + q];
        }
    }
    for (int n = 0; n < 16; ++n) {
        float a = -expf(logA[(d << 4) + n]);
        float inva = 1.f / a;
        float acc[4] = {0.f, 0.f, 0.f, 0.f};
        #pragma unroll
        for (int tau = 0; tau < 4; ++tau) {
            const int ab_base = (tau << 20) + (((d << 4) + n) << 10);
            const int bv_base = (tau << 14) + (n << 10);
            #pragma unroll
            for (int k = 0; k < 4; ++k) {
                float ab = abar[ab_base + sid[tau][k]];
                float bb = (ab - 1.f) * inva * Bv[bv_base + sid[tau][k]];
                acc[k] = fmaf(ab, acc[k], bb * uu[tau][k]);
            }
        }
        #pragma unroll
        for (int k = 0; k < 4; ++k)
            S[sbase + (n << 10) + t + (k << 8)] = f2bf(acc[k]);
    }
}

// One decode step: in-place bf16 state update + y = sum_n(s*Cv) folded into
// YMAXT via monotonic-uint atomicMax.
__global__ __launch_bounds__(256) void state_dec_k(unsigned short* __restrict__ s,
        const float* __restrict__ abar, const float* __restrict__ Bv,
        const float* __restrict__ u, const float* __restrict__ logA,
        const float* __restrict__ Cv, unsigned* __restrict__ ymaxt)
{
    const int v = blockIdx.x, d = blockIdx.y;
    const int vx = v / 5 - 2, vy = v % 5 - 2;
    const int t = threadIdx.x;
    const size_t sbase = (size_t)((v << 6) + d) << 14;
    int hw[4], sid[4];
    float ud[4], yacc[4];
    #pragma unroll
    for (int k = 0; k < 4; ++k) {
        hw[k] = t + (k << 8);
        int h = hw[k] >> 5, w = hw[k] & 31;
        sid[k] = (((h + vy + 32) & 31) << 5) | ((w + vx + 32) & 31);
        ud[k] = u[(d << 10) + hw[k]];
        yacc[k] = 0.f;
    }
    float sn[16][4];
    #pragma unroll
    for (int n = 0; n < 16; ++n) {
        float a = -expf(logA[(d << 4) + n]);
        float inva = 1.f / a;
        const int pb = ((d << 4) + n) << 10;
        #pragma unroll
        for (int k = 0; k < 4; ++k) {
            float ab = abar[pb + hw[k]];
            float bb = (ab - 1.f) * inva * Bv[(n << 10) + hw[k]];
            float sv = bf2f(s[sbase + (n << 10) + sid[k]]);
            float ns = fmaf(ab, sv, bb * ud[k]);
            sn[n][k] = ns;
            yacc[k] = fmaf(ns, Cv[(n << 10) + hw[k]], yacc[k]);
        }
    }
    __syncthreads();   // all slab reads drained before any in-place write
    #pragma unroll
    for (int n = 0; n < 16; ++n)
        #pragma unroll
        for (int k = 0; k < 4; ++k)
            s[sbase + (n << 10) + hw[k]] = f2bf(sn[n][k]);
    #pragma unroll
    for (int k = 0; k < 4; ++k)
        atomicMax(&ymaxt[(d << 10) + hw[k]], f2ord(yacc[k]));
}

// Decoder conv1: CIN=64 conv whose input is ord2f(YMAXT) + u*Dskip, built
// during LDS staging.
__global__ __launch_bounds__(256) void dec1_k(const unsigned* __restrict__ ymaxt,
        const float* __restrict__ u, const float* __restrict__ Dskip,
        const float* __restrict__ wgt, const float* __restrict__ bias,
        float* __restrict__ out)
{
    __shared__ float smem[32 * 320];
    const int co = blockIdx.x;
    const int rb = blockIdx.y * 8;
    const int t = threadIdx.x;
    const int c = t & 31, lr = t >> 5;
    const int cm1 = (c + 31) & 31, cp1 = (c + 1) & 31;
    const float* wg = wgt + co * 576;
    float acc = 0.f;
    for (int c0 = 0; c0 < 64; c0 += 32) {
        if (c0) __syncthreads();
        for (int idx = t; idx < 32 * 320; idx += 256) {
            int ci  = idx / 320;
            int rem = idx - ci * 320;
            int gr  = (rb - 1 + (rem >> 5)) & 31;
            int g   = ((c0 + ci) << 10) + (gr << 5) + (rem & 31);
            smem[idx] = ord2f(ymaxt[g]) + u[g] * Dskip[c0 + ci];
        }
        __syncthreads();
        for (int ci = 0; ci < 32; ++ci) {
            const float* lp = smem + ci * 320 + lr * 32;
            const float* wp = wg + (c0 + ci) * 9;
            acc += wp[0]*lp[cm1]    + wp[1]*lp[c]    + wp[2]*lp[cp1];
            acc += wp[3]*lp[32+cm1] + wp[4]*lp[32+c] + wp[5]*lp[32+cp1];
            acc += wp[6]*lp[64+cm1] + wp[7]*lp[64+c] + wp[8]*lp[64+cp1];
        }
    }
    acc = fmaxf(acc + bias[co], 0.f);
    out[(co << 10) + ((rb + lr) << 5) + c] = acc;
}

// ---------------------------------------------------------------------------
extern "C" void kernel_launch(void* const* d_in, const int* in_sizes, int n_in,
                              void* d_out, int out_size, void* d_ws, size_t ws_size,
                              hipStream_t stream)
{
    const float* input_seq = (const float*)d_in[0];
    const float* enc_w1 = (const float*)d_in[1];
    const float* enc_b1 = (const float*)d_in[2];
    const float* enc_w2 = (const float*)d_in[3];
    const float* enc_b2 = (const float*)d_in[4];
    const float* wd     = (const float*)d_in[5];
    const float* bd     = (const float*)d_in[6];
    const float* wB     = (const float*)d_in[7];
    const float* wC     = (const float*)d_in[8];
    const float* logA   = (const float*)d_in[9];
    const float* Dskip  = (const float*)d_in[10];
    const float* dtinv  = (const float*)d_in[11];
    const float* dec_w1 = (const float*)d_in[12];
    const float* dec_b1 = (const float*)d_in[13];
    const float* dec_w2 = (const float*)d_in[14];
    const float* dec_b2 = (const float*)d_in[15];
    const float* dec_w3 = (const float*)d_in[16];
    const float* dec_b3 = (const float*)d_in[17];

    char* ws = (char*)d_ws;
    unsigned short* S  = (unsigned short*)ws;                 // 52,428,800 B
    float* ABAR = (float*)(ws + 52428800);                    // 16,777,216 B
    float* BV   = (float*)(ws + 52428800 + 16777216);         //    262,144 B
    float* CV   = BV + 4 * 16 * 1024;                         //    262,144 B
    float* U    = CV + 4 * 16 * 1024;                         //  1,048,576 B
    float* X1   = U + 4 * 64 * 1024;                          //  1,048,576 B
    unsigned* YMAXT = (unsigned*)(X1 + 4 * 64 * 1024);        //    262,144 B
    float* D1   = (float*)(YMAXT + 64 * 1024);                //    262,144 B
    float* D2   = D1 + 64 * 1024;                             //    262,144 B
    float* outp = (float*)d_out;                              // 4*1024 f32

    // ---- Encode phase: 4 kernels total ----
    conv3x3_k<1, 1><<<dim3(64, 4, 4), 256, 0, stream>>>(input_seq, enc_w1, enc_b1, X1);
    conv3x3_k<64, 1><<<dim3(64, 4, 4), 256, 0, stream>>>(X1, enc_w2, enc_b2, U);
    cellconv_k<<<dim3(96, 4, 4), 256, 0, stream>>>(U, wd, bd, wB, wC, logA, dtinv,
                                                   ABAR, BV, CV, YMAXT, 0);
    state4_k<<<dim3(25, 64), 256, 0, stream>>>(S, ABAR, BV, U, logA);

    // ---- Decode phase: 7 kernels per step ----
    for (int tt = 0; tt < 4; ++tt) {
        const float* src = (tt == 0) ? (input_seq + 3 * 1024) : (outp + (tt - 1) * 1024);
        conv3x3_k<1, 1><<<dim3(64, 4, 1), 256, 0, stream>>>(src, enc_w1, enc_b1, X1);
        conv3x3_k<64, 1><<<dim3(64, 4, 1), 256, 0, stream>>>(X1, enc_w2, enc_b2, U);
        cellconv_k<<<dim3(96, 4, 1), 256, 0, stream>>>(U, wd, bd, wB, wC, logA, dtinv,
                                                       ABAR, BV, CV, YMAXT, 1);
        state_dec_k<<<dim3(25, 64), 256, 0, stream>>>(S, ABAR, BV, U, logA, CV, YMAXT);
        dec1_k<<<dim3(64, 4), 256, 0, stream>>>(YMAXT, U, Dskip, dec_w1, dec_b1, D1);
        conv3x3_k<64, 1><<<dim3(64, 4, 1), 256, 0, stream>>>(D1, dec_w2, dec_b2, D2);
        conv3x3_k<64, 0><<<dim3(1, 4, 1), 256, 0, stream>>>(D2, dec_w3, dec_b3,
                                                            outp + tt * 1024);
    }
}